// Round 5
// baseline (37.401 us; speedup 1.0000x reference)
//
#include <hip/hip_runtime.h>

// T_lv2: out[0..4718591]        = fold(gather(unfold(ref_lv2,3,1,1)))/9  [4,128,96,96]
// T_lv1: out[4718592..9437183]  = fold(gather(unfold(ref_lv1,6,2,2)))/9  [4,64,192,192]
//
// R4: 73.7KB LDS blocks (2 resident/CU -> stage/gather overlap across blocks),
// 512 blocks (exactly 2 per CU), 512 threads. Cells are 4 bf16 (8B):
//  - lv1 (bid<256):  (b, parity q, ch-pair) ; cell(ysh,xsh) = {c0,c1}x{x0,x1}
//  - lv2 (bid>=256): (b, 4-ch group, pos-half); cell(ys,xs) = {c0..c3}
// Random per-tap ds_read_b64 serves 4 output values.

typedef float f2 __attribute__((ext_vector_type(2)));
typedef float f4 __attribute__((ext_vector_type(4)));

#define NINE_INV (1.0f / 9.0f)

__device__ __forceinline__ unsigned rne_bf16(float f) {
    unsigned u = __builtin_bit_cast(unsigned, f);
    return (u + 0x7fffu + ((u >> 16) & 1u)) >> 16;
}
__device__ __forceinline__ unsigned pack_bf2(float a, float b) {
    return rne_bf16(a) | (rne_bf16(b) << 16);
}
__device__ __forceinline__ f2 up2(unsigned w) {
    f2 r;
    r.x = __builtin_bit_cast(float, w << 16);
    r.y = __builtin_bit_cast(float, w & 0xffff0000u);
    return r;
}

__global__ __launch_bounds__(512, 4) void transfer_kernel(
    const int* __restrict__ idx,      // [4, 9216]
    const float* __restrict__ ref1,   // [4,64,192,192]
    const float* __restrict__ ref2,   // [4,128,96,96]
    float* __restrict__ out)
{
    __shared__ __align__(16) unsigned s2[18432];   // 9216 cells x 2 words (4 bf16)
    const int tid = threadIdx.x;
    const int bid = blockIdx.x;

    if (bid < 256) {
        // ---------------- lv1: b, parity q, channel pair ----------------
        const int b = bid & 3, q = (bid >> 2) & 1, c0 = (bid >> 3) * 2;
        const float* g0 = ref1 + (size_t)(b * 64 + c0) * 36864;

        // Stage: two cells (xsh0, xsh0+1) per iter via dwordx4 row loads.
        for (int u2 = tid; u2 < 4608; u2 += 512) {
            int ysh = u2 / 48, xsh0 = 2 * (u2 - 48 * ysh);
            const float* gp = g0 + (size_t)(2 * ysh + q) * 192 + 2 * xsh0;
            f4 va = *(const f4*)gp;            // ch0, x = 2xsh0 .. 2xsh0+3
            f4 vb = *(const f4*)(gp + 36864);  // ch1
            uint4 w;
            w.x = pack_bf2(va.x, va.y); w.y = pack_bf2(vb.x, vb.y);
            w.z = pack_bf2(va.z, va.w); w.w = pack_bf2(vb.z, vb.w);
            *(uint4*)(s2 + 4 * u2) = w;
        }
        __syncthreads();

        const int* idxb = idx + b * 9216;
        float* ob = out + 4718592 + (size_t)(b * 64 + c0) * 36864;

        for (int u = tid; u < 9216; u += 512) {
            int r = u / 96, t = u - 96 * r;
            f2 a0 = {0.f, 0.f}, a1 = {0.f, 0.f};
#pragma unroll
            for (int i = 0; i < 3; ++i) {
                int oy = r - 1 + i;
                bool oyv = (unsigned)oy < 96u;
#pragma unroll
                for (int j = 0; j < 3; ++j) {
                    int ox = t - 1 + j;
                    bool pv = oyv & ((unsigned)ox < 96u);
                    int jv = idxb[pv ? oy * 96 + ox : 0];
                    int jy = jv / 96, jx = jv - 96 * jy;
                    int ysh = jy + 1 - i, xsh = jx + 1 - j;
                    bool sv = pv & ((unsigned)ysh < 96u) & ((unsigned)xsh < 96u);
                    int cell = sv ? ysh * 96 + xsh : 0;
                    float m = sv ? NINE_INV : 0.f;
                    f2 mm = {m, m};
                    uint2 w = *(const uint2*)(s2 + 2 * cell);   // random b64
                    a0 += mm * up2(w.x);
                    a1 += mm * up2(w.y);
                }
            }
            int y = 2 * r + q, x0 = 2 * t;
            float* op = ob + (size_t)y * 192 + x0;
            *(f2*)op = a0;
            *(f2*)(op + 36864) = a1;
        }
    } else {
        // ---------------- lv2: b, 4-ch group, position half ----------------
        const int r2 = bid - 256;
        const int b = r2 & 3, grp = (r2 >> 2) & 31, h = (r2 >> 7) & 1;
        const int c0 = grp * 4;
        const float* g0 = ref2 + (size_t)(b * 128 + c0) * 9216;

        // Stage full 4-channel plane: two cells per iter via f2 plane loads.
        for (int u2 = tid; u2 < 4608; u2 += 512) {
            f2 p0 = *(const f2*)(g0 + 2 * u2);
            f2 p1 = *(const f2*)(g0 + 9216 + 2 * u2);
            f2 p2 = *(const f2*)(g0 + 2 * 9216 + 2 * u2);
            f2 p3 = *(const f2*)(g0 + 3 * 9216 + 2 * u2);
            uint4 w;
            w.x = pack_bf2(p0.x, p1.x); w.y = pack_bf2(p2.x, p3.x);
            w.z = pack_bf2(p0.y, p1.y); w.w = pack_bf2(p2.y, p3.y);
            *(uint4*)(s2 + 4 * u2) = w;
        }
        __syncthreads();

        const int* idxb = idx + b * 9216;
        float* ob = out + (size_t)(b * 128 + c0) * 9216;

        const int u0 = h * 4608, u1 = u0 + 4608;
        for (int u = u0 + tid; u < u1; u += 512) {
            int y = u / 96, x = u - 96 * y;
            f2 a0 = {0.f, 0.f}, a1 = {0.f, 0.f};
#pragma unroll
            for (int i = 0; i < 3; ++i) {
                int oy = y - 1 + i;
                bool oyv = (unsigned)oy < 96u;
#pragma unroll
                for (int j = 0; j < 3; ++j) {
                    int ox = x - 1 + j;
                    bool pv = oyv & ((unsigned)ox < 96u);
                    int jv = idxb[pv ? oy * 96 + ox : 0];
                    int jy = jv / 96, jx = jv - 96 * jy;
                    int ys = y + jy - oy, xs = x + jx - ox;
                    bool sv = pv & ((unsigned)ys < 96u) & ((unsigned)xs < 96u);
                    int cell = sv ? ys * 96 + xs : 0;
                    float m = sv ? NINE_INV : 0.f;
                    f2 mm = {m, m};
                    uint2 w = *(const uint2*)(s2 + 2 * cell);   // random b64
                    a0 += mm * up2(w.x);
                    a1 += mm * up2(w.y);
                }
            }
            float* op = ob + u;
            op[0]        = a0.x; op[9216]     = a0.y;
            op[2 * 9216] = a1.x; op[3 * 9216] = a1.y;
        }
    }
}

extern "C" void kernel_launch(void* const* d_in, const int* in_sizes, int n_in,
                              void* d_out, int out_size, void* d_ws, size_t ws_size,
                              hipStream_t stream) {
    const int*   idx  = (const int*)d_in[0];   // R_lv2_star_arg [4,9216]
    const float* ref1 = (const float*)d_in[2]; // ref_lv1 [4,64,192,192]
    const float* ref2 = (const float*)d_in[3]; // ref_lv2 [4,128,96,96]
    float* outp = (float*)d_out;

    hipLaunchKernelGGL(transfer_kernel, dim3(512), dim3(512), 0, stream,
                       idx, ref1, ref2, outp);
}

// Round 6
// 31.281 us; speedup vs baseline: 1.1957x; 1.1957x over previous
//
#include <hip/hip_runtime.h>

// T_lv2: out[0..4718591]        = fold(gather(unfold(ref_lv2,3,1,1)))/9  [4,128,96,96]
// T_lv1: out[4718592..9437183]  = fold(gather(unfold(ref_lv1,6,2,2)))/9  [4,64,192,192]
//
// R5: per-tap LDS byte-offsets precomputed into a table (d_ws). Key algebra:
// for BOTH levels the tap source cell is (jy+1-i, jx+1-j) with validity
// (patch in [0,96)^2) & (cell in [0,96)^2) -> one table serves lv1 and lv2.
// Invalid taps point at a zero cell; the 1/9 scale is applied once at the end.
// Main kernel: 512 blocks x 512 thr, 73.75KB LDS (2 blocks/CU), bf16 4-value
// 8B cells, random ds_read_b64 per tap.

typedef float f2 __attribute__((ext_vector_type(2)));
typedef float f4 __attribute__((ext_vector_type(4)));

#define NINE_INV (1.0f / 9.0f)
#define ZOFF 73728u   // 9216*8: byte offset of the zero cell

__device__ __forceinline__ unsigned rne_bf16(float f) {
    unsigned u = __builtin_bit_cast(unsigned, f);
    return (u + 0x7fffu + ((u >> 16) & 1u)) >> 16;
}
__device__ __forceinline__ unsigned pack_bf2(float a, float b) {
    return rne_bf16(a) | (rne_bf16(b) << 16);
}
__device__ __forceinline__ f2 up2(unsigned w) {
    f2 r;
    r.x = __builtin_bit_cast(float, w << 16);
    r.y = __builtin_bit_cast(float, w & 0xffff0000u);
    return r;
}

// tab[b][p][u], p = i*3+j : LDS byte offset of tap source cell (or ZOFF).
__global__ __launch_bounds__(256) void table_kernel(
    const int* __restrict__ idx, unsigned* __restrict__ tab)
{
    int g = blockIdx.x * 256 + threadIdx.x;       // 0..36863
    int b = g >> 13 >= 0 ? g / 9216 : 0;          // b = g/9216
    int u = g - b * 9216;
    const int* idxb = idx + b * 9216;
    unsigned* tb = tab + (size_t)b * 9 * 9216;
    int r = u / 96, t = u - 96 * r;
#pragma unroll
    for (int i = 0; i < 3; ++i) {
        int oy = r - 1 + i;
        bool oyv = (unsigned)oy < 96u;
#pragma unroll
        for (int j = 0; j < 3; ++j) {
            int ox = t - 1 + j;
            bool pv = oyv & ((unsigned)ox < 96u);
            int jv = idxb[pv ? oy * 96 + ox : 0];
            int jy = jv / 96, jx = jv - 96 * jy;
            int ysh = jy + 1 - i, xsh = jx + 1 - j;
            bool sv = pv & ((unsigned)ysh < 96u) & ((unsigned)xsh < 96u);
            tb[(i * 3 + j) * 9216 + u] = sv ? (unsigned)((ysh * 96 + xsh) * 8) : ZOFF;
        }
    }
}

template <bool TAB>
__global__ __launch_bounds__(512) void transfer_kernel(
    const int* __restrict__ idx,      // [4, 9216]
    const float* __restrict__ ref1,   // [4,64,192,192]
    const float* __restrict__ ref2,   // [4,128,96,96]
    const unsigned* __restrict__ tab, // [4][9][9216] LDS byte offsets
    float* __restrict__ out)
{
    __shared__ __align__(16) unsigned s2[18436];   // 9217 cells x 2 words (+pad)
    const int tid = threadIdx.x;
    const int bid = blockIdx.x;
    const int b = bid & 3;

    if (tid < 4) s2[18432 + tid] = 0;              // zero cell (+pad)

    const unsigned* tb = tab + (size_t)b * 9 * 9216;
    const int* idxb = idx + b * 9216;

    if (bid < 256) {
        // ---------------- lv1: b, parity q, channel pair ----------------
        const int q = (bid >> 2) & 1, c0 = (bid >> 3) * 2;
        const float* g0 = ref1 + (size_t)(b * 64 + c0) * 36864;

        for (int u2 = tid; u2 < 4608; u2 += 512) {
            int ysh = u2 / 48, xsh0 = 2 * (u2 - 48 * ysh);
            const float* gp = g0 + (size_t)(2 * ysh + q) * 192 + 2 * xsh0;
            f4 va = *(const f4*)gp;            // ch0, x = 2xsh0 .. 2xsh0+3
            f4 vb = *(const f4*)(gp + 36864);  // ch1
            uint4 w;
            w.x = pack_bf2(va.x, va.y); w.y = pack_bf2(vb.x, vb.y);
            w.z = pack_bf2(va.z, va.w); w.w = pack_bf2(vb.z, vb.w);
            *(uint4*)(s2 + 4 * u2) = w;
        }
        __syncthreads();

        float* ob = out + 4718592 + (size_t)(b * 64 + c0) * 36864;

        for (int u = tid; u < 9216; u += 512) {
            unsigned o[9];
            if (TAB) {
#pragma unroll
                for (int p = 0; p < 9; ++p) o[p] = tb[p * 9216 + u];
            } else {
                int r = u / 96, t = u - 96 * r;
#pragma unroll
                for (int i = 0; i < 3; ++i) {
                    int oy = r - 1 + i;
                    bool oyv = (unsigned)oy < 96u;
#pragma unroll
                    for (int j = 0; j < 3; ++j) {
                        int ox = t - 1 + j;
                        bool pv = oyv & ((unsigned)ox < 96u);
                        int jv = idxb[pv ? oy * 96 + ox : 0];
                        int jy = jv / 96, jx = jv - 96 * jy;
                        int ysh = jy + 1 - i, xsh = jx + 1 - j;
                        bool sv = pv & ((unsigned)ysh < 96u) & ((unsigned)xsh < 96u);
                        o[i * 3 + j] = sv ? (unsigned)((ysh * 96 + xsh) * 8) : ZOFF;
                    }
                }
            }
            f2 a0 = {0.f, 0.f}, a1 = {0.f, 0.f};
#pragma unroll
            for (int p = 0; p < 9; ++p) {
                uint2 w = *(const uint2*)((const char*)s2 + o[p]);  // random b64
                a0 += up2(w.x);
                a1 += up2(w.y);
            }
            f2 nv = {NINE_INV, NINE_INV};
            a0 *= nv; a1 *= nv;
            int r = u / 96, t = u - 96 * r;
            int y = 2 * r + q, x0 = 2 * t;
            float* op = ob + (size_t)y * 192 + x0;
            *(f2*)op = a0;
            *(f2*)(op + 36864) = a1;
        }
    } else {
        // ---------------- lv2: b, 4-ch group, position half ----------------
        const int r2 = bid - 256;
        const int grp = (r2 >> 2) & 31, h = (r2 >> 7) & 1;
        const int c0 = grp * 4;
        const float* g0 = ref2 + (size_t)(b * 128 + c0) * 9216;

        for (int u2 = tid; u2 < 4608; u2 += 512) {
            f2 p0 = *(const f2*)(g0 + 2 * u2);
            f2 p1 = *(const f2*)(g0 + 9216 + 2 * u2);
            f2 p2 = *(const f2*)(g0 + 2 * 9216 + 2 * u2);
            f2 p3 = *(const f2*)(g0 + 3 * 9216 + 2 * u2);
            uint4 w;
            w.x = pack_bf2(p0.x, p1.x); w.y = pack_bf2(p2.x, p3.x);
            w.z = pack_bf2(p0.y, p1.y); w.w = pack_bf2(p2.y, p3.y);
            *(uint4*)(s2 + 4 * u2) = w;
        }
        __syncthreads();

        float* ob = out + (size_t)(b * 128 + c0) * 9216;

        const int u0 = h * 4608, u1 = u0 + 4608;
        for (int u = u0 + tid; u < u1; u += 512) {
            unsigned o[9];
            if (TAB) {
#pragma unroll
                for (int p = 0; p < 9; ++p) o[p] = tb[p * 9216 + u];
            } else {
                int y = u / 96, x = u - 96 * y;
#pragma unroll
                for (int i = 0; i < 3; ++i) {
                    int oy = y - 1 + i;
                    bool oyv = (unsigned)oy < 96u;
#pragma unroll
                    for (int j = 0; j < 3; ++j) {
                        int ox = x - 1 + j;
                        bool pv = oyv & ((unsigned)ox < 96u);
                        int jv = idxb[pv ? oy * 96 + ox : 0];
                        int jy = jv / 96, jx = jv - 96 * jy;
                        int ys = jy + 1 - i, xs = jx + 1 - j;
                        bool sv = pv & ((unsigned)ys < 96u) & ((unsigned)xs < 96u);
                        o[i * 3 + j] = sv ? (unsigned)((ys * 96 + xs) * 8) : ZOFF;
                    }
                }
            }
            f2 a0 = {0.f, 0.f}, a1 = {0.f, 0.f};
#pragma unroll
            for (int p = 0; p < 9; ++p) {
                uint2 w = *(const uint2*)((const char*)s2 + o[p]);  // random b64
                a0 += up2(w.x);
                a1 += up2(w.y);
            }
            f2 nv = {NINE_INV, NINE_INV};
            a0 *= nv; a1 *= nv;
            float* op = ob + u;
            op[0]        = a0.x; op[9216]     = a0.y;
            op[2 * 9216] = a1.x; op[3 * 9216] = a1.y;
        }
    }
}

extern "C" void kernel_launch(void* const* d_in, const int* in_sizes, int n_in,
                              void* d_out, int out_size, void* d_ws, size_t ws_size,
                              hipStream_t stream) {
    const int*   idx  = (const int*)d_in[0];   // R_lv2_star_arg [4,9216]
    const float* ref1 = (const float*)d_in[2]; // ref_lv1 [4,64,192,192]
    const float* ref2 = (const float*)d_in[3]; // ref_lv2 [4,128,96,96]
    float* outp = (float*)d_out;
    unsigned* tab = (unsigned*)d_ws;

    const size_t need = (size_t)4 * 9 * 9216 * sizeof(unsigned);  // 1.33 MB
    if (ws_size >= need) {
        hipLaunchKernelGGL(table_kernel, dim3(144), dim3(256), 0, stream, idx, tab);
        hipLaunchKernelGGL(transfer_kernel<true>, dim3(512), dim3(512), 0, stream,
                           idx, ref1, ref2, tab, outp);
    } else {
        hipLaunchKernelGGL(transfer_kernel<false>, dim3(512), dim3(512), 0, stream,
                           idx, ref1, ref2, tab, outp);
    }
}

// Round 7
// 28.056 us; speedup vs baseline: 1.3331x; 1.1149x over previous
//
#include <hip/hip_runtime.h>

// T_lv2: out[0..4718591]        = fold(gather(unfold(ref_lv2,3,1,1)))/9  [4,128,96,96]
// T_lv1: out[4718592..9437183]  = fold(gather(unfold(ref_lv1,6,2,2)))/9  [4,64,192,192]
//
// R6: tap table packed as u16 cell indices, position-major:
//   tabA[b][u] = uint4 (taps 0..7 as 8 x u16), tabB[b][u] = u16 (tap 8)
// -> 2 coalesced loads per position (was 9), software-pipelined one position
// ahead so L2 latency hides under the 9 ds_read_b64 + unpack of the current
// position. Non-temporal ref loads / output stores keep the table L2-hot.
// Cells: 4 bf16 (8B); sentinel cell 9216 is zeroed. Scale 1/9 applied once.

typedef float f2 __attribute__((ext_vector_type(2)));
typedef float f4 __attribute__((ext_vector_type(4)));

#define NINE_INV (1.0f / 9.0f)
#define ZCELL 9216u

__device__ __forceinline__ unsigned rne_bf16(float f) {
    unsigned u = __builtin_bit_cast(unsigned, f);
    return (u + 0x7fffu + ((u >> 16) & 1u)) >> 16;
}
__device__ __forceinline__ unsigned pack_bf2(float a, float b) {
    return rne_bf16(a) | (rne_bf16(b) << 16);
}
__device__ __forceinline__ f2 up2(unsigned w) {
    f2 r;
    r.x = __builtin_bit_cast(float, w << 16);
    r.y = __builtin_bit_cast(float, w & 0xffff0000u);
    return r;
}
template <typename T> __device__ __forceinline__ T ntload(const T* p) {
    return __builtin_nontemporal_load(p);
}
template <typename T> __device__ __forceinline__ void ntstore(T* p, T v) {
    __builtin_nontemporal_store(v, p);
}

// Build the packed tap table.
__global__ __launch_bounds__(256) void table_kernel(
    const int* __restrict__ idx, uint4* __restrict__ tabA,
    unsigned short* __restrict__ tabB)
{
    int g = blockIdx.x * 256 + threadIdx.x;       // 0..36863
    int b = g / 9216;
    int u = g - b * 9216;
    const int* idxb = idx + b * 9216;
    int r = u / 96, t = u - 96 * r;
    unsigned e[9];
#pragma unroll
    for (int i = 0; i < 3; ++i) {
        int oy = r - 1 + i;
        bool oyv = (unsigned)oy < 96u;
#pragma unroll
        for (int j = 0; j < 3; ++j) {
            int ox = t - 1 + j;
            bool pv = oyv & ((unsigned)ox < 96u);
            int jv = idxb[pv ? oy * 96 + ox : 0];
            int jy = jv / 96, jx = jv - 96 * jy;
            int ysh = jy + 1 - i, xsh = jx + 1 - j;
            bool sv = pv & ((unsigned)ysh < 96u) & ((unsigned)xsh < 96u);
            e[i * 3 + j] = sv ? (unsigned)(ysh * 96 + xsh) : ZCELL;
        }
    }
    uint4 w;
    w.x = e[0] | (e[1] << 16);
    w.y = e[2] | (e[3] << 16);
    w.z = e[4] | (e[5] << 16);
    w.w = e[6] | (e[7] << 16);
    tabA[g] = w;
    tabB[g] = (unsigned short)e[8];
}

template <bool TAB>
__global__ __launch_bounds__(512, 4) void transfer_kernel(
    const int* __restrict__ idx,      // [4, 9216]
    const float* __restrict__ ref1,   // [4,64,192,192]
    const float* __restrict__ ref2,   // [4,128,96,96]
    const uint4* __restrict__ tabA,   // [4][9216] taps 0..7
    const unsigned short* __restrict__ tabB, // [4][9216] tap 8
    float* __restrict__ out)
{
    __shared__ __align__(16) unsigned s2[18436];   // 9217 cells x 2 words (+pad)
    const int tid = threadIdx.x;
    const int bid = blockIdx.x;
    const int b = bid & 3;

    if (tid < 4) s2[18432 + tid] = 0;              // zero cell (+pad)

    const uint4* tA = tabA + b * 9216;
    const unsigned short* tB = tabB + b * 9216;
    const int* idxb = idx + b * 9216;

    // inline fallback offset computation (cell index, ZCELL if invalid)
    auto inline_cells = [&](int u, unsigned* e) {
        int r = u / 96, t = u - 96 * r;
#pragma unroll
        for (int i = 0; i < 3; ++i) {
            int oy = r - 1 + i;
            bool oyv = (unsigned)oy < 96u;
#pragma unroll
            for (int j = 0; j < 3; ++j) {
                int ox = t - 1 + j;
                bool pv = oyv & ((unsigned)ox < 96u);
                int jv = idxb[pv ? oy * 96 + ox : 0];
                int jy = jv / 96, jx = jv - 96 * jy;
                int ysh = jy + 1 - i, xsh = jx + 1 - j;
                bool sv = pv & ((unsigned)ysh < 96u) & ((unsigned)xsh < 96u);
                e[i * 3 + j] = sv ? (unsigned)(ysh * 96 + xsh) : ZCELL;
            }
        }
    };

    auto do_taps = [&](const unsigned* cw, unsigned c8, f2& a0, f2& a1) {
#pragma unroll
        for (int q = 0; q < 4; ++q) {
            unsigned lo = cw[q] & 0xffffu, hi = cw[q] >> 16;
            uint2 wa = *(const uint2*)((const char*)s2 + (lo << 3));
            uint2 wb = *(const uint2*)((const char*)s2 + (hi << 3));
            a0 += up2(wa.x); a1 += up2(wa.y);
            a0 += up2(wb.x); a1 += up2(wb.y);
        }
        uint2 wc = *(const uint2*)((const char*)s2 + (c8 << 3));
        a0 += up2(wc.x); a1 += up2(wc.y);
    };

    if (bid < 256) {
        // ---------------- lv1: b, parity q, channel pair ----------------
        const int q = (bid >> 2) & 1, c0 = (bid >> 3) * 2;
        const float* g0 = ref1 + (size_t)(b * 64 + c0) * 36864;

        for (int u2 = tid; u2 < 4608; u2 += 512) {
            int ysh = u2 / 48, xsh0 = 2 * (u2 - 48 * ysh);
            const float* gp = g0 + (size_t)(2 * ysh + q) * 192 + 2 * xsh0;
            f4 va = ntload((const f4*)gp);            // ch0
            f4 vb = ntload((const f4*)(gp + 36864));  // ch1
            uint4 w;
            w.x = pack_bf2(va.x, va.y); w.y = pack_bf2(vb.x, vb.y);
            w.z = pack_bf2(va.z, va.w); w.w = pack_bf2(vb.z, vb.w);
            *(uint4*)(s2 + 4 * u2) = w;
        }
        __syncthreads();

        float* ob = out + 4718592 + (size_t)(b * 64 + c0) * 36864;

        uint4 cA; unsigned cB;
        if (TAB) { cA = tA[tid]; cB = tB[tid]; }
        int u = tid;
#pragma unroll 2
        for (int k = 0; k < 18; ++k) {
            uint4 nA = cA; unsigned nB = cB;
            if (TAB && k < 17) { nA = tA[u + 512]; nB = tB[u + 512]; }
            unsigned cw[4];
            unsigned c8;
            if (TAB) {
                cw[0] = cA.x; cw[1] = cA.y; cw[2] = cA.z; cw[3] = cA.w; c8 = cB;
            } else {
                unsigned e[9];
                inline_cells(u, e);
                cw[0] = e[0] | (e[1] << 16); cw[1] = e[2] | (e[3] << 16);
                cw[2] = e[4] | (e[5] << 16); cw[3] = e[6] | (e[7] << 16);
                c8 = e[8];
            }
            f2 a0 = {0.f, 0.f}, a1 = {0.f, 0.f};
            do_taps(cw, c8, a0, a1);
            f2 nv = {NINE_INV, NINE_INV};
            a0 *= nv; a1 *= nv;
            int r = u / 96, t = u - 96 * r;
            float* op = ob + (size_t)(2 * r + q) * 192 + 2 * t;
            ntstore((f2*)op, a0);
            ntstore((f2*)(op + 36864), a1);
            u += 512; cA = nA; cB = nB;
        }
    } else {
        // ---------------- lv2: b, 4-ch group, position half ----------------
        const int r2 = bid - 256;
        const int grp = (r2 >> 2) & 31, h = (r2 >> 7) & 1;
        const int c0 = grp * 4;
        const float* g0 = ref2 + (size_t)(b * 128 + c0) * 9216;

        for (int u2 = tid; u2 < 4608; u2 += 512) {
            f2 p0 = ntload((const f2*)(g0 + 2 * u2));
            f2 p1 = ntload((const f2*)(g0 + 9216 + 2 * u2));
            f2 p2 = ntload((const f2*)(g0 + 2 * 9216 + 2 * u2));
            f2 p3 = ntload((const f2*)(g0 + 3 * 9216 + 2 * u2));
            uint4 w;
            w.x = pack_bf2(p0.x, p1.x); w.y = pack_bf2(p2.x, p3.x);
            w.z = pack_bf2(p0.y, p1.y); w.w = pack_bf2(p2.y, p3.y);
            *(uint4*)(s2 + 4 * u2) = w;
        }
        __syncthreads();

        float* ob = out + (size_t)(b * 128 + c0) * 9216;

        const int u0 = h * 4608;
        uint4 cA; unsigned cB;
        if (TAB) { cA = tA[u0 + tid]; cB = tB[u0 + tid]; }
        int u = u0 + tid;
#pragma unroll 2
        for (int k = 0; k < 9; ++k) {
            uint4 nA = cA; unsigned nB = cB;
            if (TAB && k < 8) { nA = tA[u + 512]; nB = tB[u + 512]; }
            unsigned cw[4];
            unsigned c8;
            if (TAB) {
                cw[0] = cA.x; cw[1] = cA.y; cw[2] = cA.z; cw[3] = cA.w; c8 = cB;
            } else {
                unsigned e[9];
                inline_cells(u, e);
                cw[0] = e[0] | (e[1] << 16); cw[1] = e[2] | (e[3] << 16);
                cw[2] = e[4] | (e[5] << 16); cw[3] = e[6] | (e[7] << 16);
                c8 = e[8];
            }
            f2 a0 = {0.f, 0.f}, a1 = {0.f, 0.f};
            do_taps(cw, c8, a0, a1);
            f2 nv = {NINE_INV, NINE_INV};
            a0 *= nv; a1 *= nv;
            float* op = ob + u;
            ntstore(op, a0.x);          ntstore(op + 9216, a0.y);
            ntstore(op + 2 * 9216, a1.x); ntstore(op + 3 * 9216, a1.y);
            u += 512; cA = nA; cB = nB;
        }
    }
}

extern "C" void kernel_launch(void* const* d_in, const int* in_sizes, int n_in,
                              void* d_out, int out_size, void* d_ws, size_t ws_size,
                              hipStream_t stream) {
    const int*   idx  = (const int*)d_in[0];   // R_lv2_star_arg [4,9216]
    const float* ref1 = (const float*)d_in[2]; // ref_lv1 [4,64,192,192]
    const float* ref2 = (const float*)d_in[3]; // ref_lv2 [4,128,96,96]
    float* outp = (float*)d_out;

    uint4* tabA = (uint4*)d_ws;                          // 4*9216*16 B
    unsigned short* tabB = (unsigned short*)((char*)d_ws + (size_t)4 * 9216 * 16);

    const size_t need = (size_t)4 * 9216 * 16 + (size_t)4 * 9216 * 2;  // 664 KB
    if (ws_size >= need) {
        hipLaunchKernelGGL(table_kernel, dim3(144), dim3(256), 0, stream,
                           idx, tabA, tabB);
        hipLaunchKernelGGL(transfer_kernel<true>, dim3(512), dim3(512), 0, stream,
                           idx, ref1, ref2, tabA, tabB, outp);
    } else {
        hipLaunchKernelGGL(transfer_kernel<false>, dim3(512), dim3(512), 0, stream,
                           idx, ref1, ref2, tabA, tabB, outp);
    }
}